// Round 10
// baseline (2517.251 us; speedup 1.0000x reference)
//
#include <hip/hip_runtime.h>
#include <stdint.h>

typedef unsigned int u32;
typedef unsigned long long u64;
typedef unsigned short ushort;
typedef __attribute__((ext_vector_type(8))) short bf16x8;
typedef __attribute__((ext_vector_type(4))) float f32x4;

#define JAX_PARTITIONABLE 1

#define HD     1024
#define BBATCH 64
#define TSTEP  32
#define VOCAB  32000
#define NROWS  2048      // TSTEP * BBATCH
#define GATE6  6144      // 6 * HD
#define NCB    250       // 32000 / 128 col-blocks
#define NCAND  16
#define GRUB   256       // persistent GRU blocks (1 per CU)

// ---------------- Threefry-2x32 (matches jax._src.prng) ----------------
__device__ __forceinline__ void threefry2x32(u32 k0, u32 k1, u32 x0, u32 x1,
                                             u32& y0, u32& y1) {
  u32 ks2 = k0 ^ k1 ^ 0x1BD11BDAu;
  x0 += k0; x1 += k1;
#define TFR(r) do { x0 += x1; x1 = (x1 << (r)) | (x1 >> (32 - (r))); x1 ^= x0; } while (0)
  TFR(13); TFR(15); TFR(26); TFR(6);   x0 += k1;  x1 += ks2 + 1u;
  TFR(17); TFR(29); TFR(16); TFR(24);  x0 += ks2; x1 += k0 + 2u;
  TFR(13); TFR(15); TFR(26); TFR(6);   x0 += k0;  x1 += k1 + 3u;
  TFR(17); TFR(29); TFR(16); TFR(24);  x0 += k1;  x1 += ks2 + 4u;
  TFR(13); TFR(15); TFR(26); TFR(6);   x0 += ks2; x1 += k0 + 5u;
#undef TFR
  y0 = x0; y1 = x1;
}

__device__ __forceinline__ u32 jax_random_bits(u32 n) {
#if JAX_PARTITIONABLE
  u32 y0, y1; threefry2x32(0u, 42u, 0u, n, y0, y1);
  return y0 ^ y1;
#else
  u32 y0, y1;
  if (n < 8192u) { threefry2x32(0u, 42u, n, n + 8192u, y0, y1); return y0; }
  else           { threefry2x32(0u, 42u, n - 8192u, n, y0, y1); return y1; }
#endif
}

// value-desc, tie -> lower vocab index wins
__device__ __forceinline__ u64 packkey(float v, int idx) {
  u32 b = __float_as_uint(v);
  b = (b & 0x80000000u) ? ~b : (b | 0x80000000u);
  return ((u64)b << 32) | (u64)(~(u32)idx);
}

__device__ __forceinline__ void insert4(u64* t4, u64 k) {
  if (k > t4[3]) {
    t4[3] = k;
    if (t4[3] > t4[2]) { u64 tm = t4[2]; t4[2] = t4[3]; t4[3] = tm; }
    if (t4[2] > t4[1]) { u64 tm = t4[1]; t4[1] = t4[2]; t4[2] = tm; }
    if (t4[1] > t4[0]) { u64 tm = t4[0]; t4[0] = t4[1]; t4[1] = tm; }
  }
}

__device__ __forceinline__ ushort f2bf_rne(float x) {
  u32 u = __float_as_uint(x);
  return (ushort)((u + 0x7fffu + ((u >> 16) & 1u)) >> 16);
}
__device__ __forceinline__ float bf2f(ushort h) {
  return __uint_as_float(((u32)h) << 16);
}

typedef const __attribute__((address_space(1))) void* gas_ptr;
typedef __attribute__((address_space(3))) void* las_ptr;
__device__ __forceinline__ void gload16(const void* g, void* l) {
  __builtin_amdgcn_global_load_lds((gas_ptr)g, (las_ptr)l, 16, 0, 0);
}

// ---------------- two-level grid barrier (8 groups by bid&7) ----------------
__device__ __forceinline__ void grid_bar2(u32* B, int nPerGrp) {
  __syncthreads();
  if (threadIdx.x == 0) {
    __threadfence();
    const int g = blockIdx.x & 7;
    u32* gc = B + g * 32;
    u32* gg = B + 256 + g * 32;
    u32 mygen = __hip_atomic_load(gg, __ATOMIC_RELAXED, __HIP_MEMORY_SCOPE_AGENT);
    u32 a = __hip_atomic_fetch_add(gc, 1u, __ATOMIC_ACQ_REL, __HIP_MEMORY_SCOPE_AGENT);
    if (a == (u32)nPerGrp - 1) {
      __hip_atomic_store(gc, 0u, __ATOMIC_RELAXED, __HIP_MEMORY_SCOPE_AGENT);
      u32* GC = B + 512; u32* GG = B + 544;
      u32 mg = __hip_atomic_load(GG, __ATOMIC_RELAXED, __HIP_MEMORY_SCOPE_AGENT);
      u32 ga = __hip_atomic_fetch_add(GC, 1u, __ATOMIC_ACQ_REL, __HIP_MEMORY_SCOPE_AGENT);
      if (ga == 7u) {
        __hip_atomic_store(GC, 0u, __ATOMIC_RELAXED, __HIP_MEMORY_SCOPE_AGENT);
        __hip_atomic_fetch_add(GG, 1u, __ATOMIC_RELEASE, __HIP_MEMORY_SCOPE_AGENT);
      } else {
        while (__hip_atomic_load(GG, __ATOMIC_ACQUIRE, __HIP_MEMORY_SCOPE_AGENT) == mg)
          __builtin_amdgcn_s_sleep(1);
      }
      __hip_atomic_fetch_add(gg, 1u, __ATOMIC_RELEASE, __HIP_MEMORY_SCOPE_AGENT);
    } else {
      while (__hip_atomic_load(gg, __ATOMIC_ACQUIRE, __HIP_MEMORY_SCOPE_AGENT) == mygen)
        __builtin_amdgcn_s_sleep(1);
    }
  }
  __syncthreads();
}

// ---------------- fp32 -> bf16 bulk convert ----------------
__global__ __launch_bounds__(256) void tobf16(const float* __restrict__ src,
                                              ushort* __restrict__ dst, int n8) {
  int i = blockIdx.x * 256 + threadIdx.x;
  const int stride = gridDim.x * 256;
  for (; i < n8; i += stride) {
    const float4* s4 = (const float4*)src + (size_t)i * 2;
    float4 a = s4[0], b = s4[1];
    u32 o0 = f2bf_rne(a.x) | ((u32)f2bf_rne(a.y) << 16);
    u32 o1 = f2bf_rne(a.z) | ((u32)f2bf_rne(a.w) << 16);
    u32 o2 = f2bf_rne(b.x) | ((u32)f2bf_rne(b.y) << 16);
    u32 o3 = f2bf_rne(b.z) | ((u32)f2bf_rne(b.w) << 16);
    ((uint4*)dst)[i] = make_uint4(o0, o1, o2, o3);
  }
}

// ------- W_ih|W_hh -> PERMUTED bf16 3-level split, 24-row block slices -----
// out row r' = b*24 + g*4 + j'  (b=0..255, g=0..5, j'=0..3)
__global__ __launch_bounds__(256) void tobf16x3_gruP24(
    const float* __restrict__ Wih, const float* __restrict__ Whh,
    ushort* __restrict__ w1, ushort* __restrict__ w2, ushort* __restrict__ w3) {
  int i = blockIdx.x * 256 + threadIdx.x;
  if (i >= GATE6 * (HD / 8)) return;
  int rp = i >> 7;           // out row
  int kc = i & 127;          // 8-elem chunk along K
  int b = rp / 24, rem = rp % 24;
  int g = rem >> 2, jp = rem & 3;
  const float* src = (g < 3)
      ? (Wih + ((size_t)g * HD + b * 4 + jp) * HD)
      : (Whh + ((size_t)(g - 3) * HD + b * 4 + jp) * HD);
  const float4* s4 = (const float4*)(src + kc * 8);
  float v[8];
  float4 a = s4[0], bb = s4[1];
  v[0]=a.x; v[1]=a.y; v[2]=a.z; v[3]=a.w; v[4]=bb.x; v[5]=bb.y; v[6]=bb.z; v[7]=bb.w;
  ushort p1[8], p2[8], p3[8];
#pragma unroll
  for (int e = 0; e < 8; ++e) {
    p1[e] = f2bf_rne(v[e]);
    float r1 = v[e] - bf2f(p1[e]);
    p2[e] = f2bf_rne(r1);
    float r2 = r1 - bf2f(p2[e]);
    p3[e] = f2bf_rne(r2);
  }
  u32 o1[4], o2[4], o3[4];
#pragma unroll
  for (int e = 0; e < 4; ++e) {
    o1[e] = p1[2*e] | ((u32)p1[2*e+1] << 16);
    o2[e] = p2[2*e] | ((u32)p2[2*e+1] << 16);
    o3[e] = p3[2*e] | ((u32)p3[2*e+1] << 16);
  }
  ((uint4*)w1)[i] = make_uint4(o1[0], o1[1], o1[2], o1[3]);
  ((uint4*)w2)[i] = make_uint4(o2[0], o2[1], o2[2], o2[3]);
  ((uint4*)w3)[i] = make_uint4(o3[0], o3[1], o3[2], o3[3]);
}

// ---------------- fc_in skinny NT GEMM (fp32, one-time) ----------------
__global__ __launch_bounds__(256) void gemm64_nt(
    const float* __restrict__ A, const float* __restrict__ B,
    float* __restrict__ part) {
  __shared__ float4 As4[64 * 33];
  __shared__ float4 Bs4[32 * 33];
  const int tid = threadIdx.x;
  const int n0 = blockIdx.x * 32;
  const float* Brow = B + (size_t)n0 * HD;
  const int ks = blockIdx.y * 256;
  const int tc = tid & 7, trg = tid >> 3;
  float acc[2][4] = {};
  for (int kc = 0; kc < 2; ++kc) {
    const int k0 = ks + kc * 128;
#pragma unroll
    for (int l = 0; l < 8; ++l) {
      int m = tid + l * 256; int row = m >> 5, k4 = m & 31;
      As4[row * 33 + k4] = *(const float4*)(A + (size_t)row * HD + k0 + k4 * 4);
    }
#pragma unroll
    for (int l = 0; l < 4; ++l) {
      int m = tid + l * 256; int row = m >> 5, k4 = m & 31;
      Bs4[row * 33 + k4] = *(const float4*)(Brow + (size_t)row * HD + k0 + k4 * 4);
    }
    __syncthreads();
#pragma unroll
    for (int kq = 0; kq < 32; ++kq) {
      float4 av[2], bv[4];
      av[0] = As4[trg * 33 + kq];
      av[1] = As4[(trg + 32) * 33 + kq];
      bv[0] = Bs4[tc * 33 + kq];
      bv[1] = Bs4[(tc + 8) * 33 + kq];
      bv[2] = Bs4[(tc + 16) * 33 + kq];
      bv[3] = Bs4[(tc + 24) * 33 + kq];
#pragma unroll
      for (int i = 0; i < 2; ++i)
#pragma unroll
        for (int j = 0; j < 4; ++j) {
          acc[i][j] += av[i].x * bv[j].x;
          acc[i][j] += av[i].y * bv[j].y;
          acc[i][j] += av[i].z * bv[j].z;
          acc[i][j] += av[i].w * bv[j].w;
        }
    }
    __syncthreads();
  }
  float* P = part + (size_t)blockIdx.y * BBATCH * HD;
#pragma unroll
  for (int i = 0; i < 2; ++i) {
    int b = trg + 32 * i;
#pragma unroll
    for (int j = 0; j < 4; ++j)
      P[(size_t)b * HD + n0 + tc + 8 * j] = acc[i][j];
  }
}

// ---------------- fc_in combine (+ 3-level split of h0) ----------------
__global__ __launch_bounds__(256) void combine_fcin(
    const float* __restrict__ part, const float* __restrict__ b_fc,
    float* __restrict__ h, ushort* __restrict__ h1, ushort* __restrict__ h2,
    ushort* __restrict__ h3) {
  int idx = blockIdx.x * 256 + threadIdx.x;
  int j = idx & 1023; int b = idx >> 10;
  const size_t S = (size_t)BBATCH * HD;
  const float* p = part + (size_t)b * HD;
  float d = p[j]; d += p[S + j]; d += p[2 * S + j]; d += p[3 * S + j];
  float hv = d + b_fc[j];
  h[idx] = hv;
  ushort a = f2bf_rne(hv);
  float r1 = hv - bf2f(a);
  ushort bb = f2bf_rne(r1);
  float r2 = r1 - bf2f(bb);
  h1[idx] = a; h2[idx] = bb; h3[idx] = f2bf_rne(r2);
}

// ---------------- persistent GRU: all 32 steps, W' resident in LDS ---------
// 256 blocks x 256 thr (4 waves). Block b owns j-cols [b*4,b*4+4) = 24 W'
// rows x 3 levels = 147 KB LDS, loaded once. h state: 1 fp32 reg per thread.
// Per step: MFMA GEMM (A = h-splits from global, B = LDS) -> C to LDS scratch
// -> in-block gate -> splits to ping-pong buffers -> grid barrier.
__global__ __launch_bounds__(256, 1) void gru_all(
    const ushort* __restrict__ W1, const ushort* __restrict__ W2,
    const ushort* __restrict__ W3,
    const float* __restrict__ b_ih, const float* __restrict__ b_hh,
    const float* __restrict__ h0,
    float* __restrict__ outs, ushort* __restrict__ outs_bf,
    ushort* __restrict__ hA1, ushort* __restrict__ hA2, ushort* __restrict__ hA3,
    ushort* __restrict__ hB1, ushort* __restrict__ hB2, ushort* __restrict__ hB3,
    u32* __restrict__ bar) {
  __shared__ ushort S[76928];               // 153856 B: W' 147456 + Cg 6400
  float* Cg = (float*)(S + 73728);          // [64][25] fp32 scratch
  const int tid = threadIdx.x;
  const int lane = tid & 63, w = tid >> 6;
  const int b = blockIdx.x;
  const int l15 = lane & 15, kc4 = lane >> 4;

  // ---- load W' slice to LDS once (source granule pre-swizzled, rule 21) ----
  {
    const ushort* Wl0 = W1 + (size_t)b * 24 * HD;
    const ushort* Wl1 = W2 + (size_t)b * 24 * HD;
    const ushort* Wl2 = W3 + (size_t)b * 24 * HD;
#pragma unroll
    for (int lv = 0; lv < 3; ++lv) {
      const ushort* Wsrc = (lv == 0) ? Wl0 : (lv == 1) ? Wl1 : Wl2;
      for (int k = 0; k < 12; ++k) {
        int gi = w * 64 + k * 256 + lane;     // granule 0..3071
        int row = gi >> 7, gc = gi & 127;
        gload16(Wsrc + (size_t)row * HD + ((gc ^ (row & 7)) * 8),
                S + lv * 24576 + (w * 64 + k * 256) * 8);
      }
    }
    asm volatile("s_waitcnt vmcnt(0)" ::: "memory");
    __syncthreads();
  }

  // ---- per-thread GRU state: element (i = tid>>2, j' = tid&3) ----
  const int gi_i = tid >> 2, gj = tid & 3;
  const int jglob = b * 4 + gj;
  float hreg = h0[gi_i * HD + jglob];
  const float bi_r = b_ih[jglob], bi_z = b_ih[HD + jglob], bi_n = b_ih[2 * HD + jglob];
  const float bh_r = b_hh[jglob], bh_z = b_hh[HD + jglob], bh_n = b_hh[2 * HD + jglob];
  const int arow = w * 16 + l15;            // GEMM A row for this lane
  const int q4 = lane >> 4;                 // C row sub-block

  for (int t = 0; t < TSTEP; ++t) {
    const ushort* c1 = (t & 1) ? hB1 : hA1;
    const ushort* c2 = (t & 1) ? hB2 : hA2;
    const ushort* c3 = (t & 1) ? hB3 : hA3;
    ushort* n1 = (t & 1) ? hA1 : hB1;
    ushort* n2 = (t & 1) ? hA2 : hB2;
    ushort* n3 = (t & 1) ? hA3 : hB3;

    // ---- GEMM: C[64][24] = h_splits @ W'^T (6-product 3-split emulation) ----
    f32x4 acc[2];
    acc[0] = (f32x4){0.f, 0.f, 0.f, 0.f};
    acc[1] = (f32x4){0.f, 0.f, 0.f, 0.f};
    const ushort* a1p = c1 + (size_t)arow * HD;
    const ushort* a2p = c2 + (size_t)arow * HD;
    const ushort* a3p = c3 + (size_t)arow * HD;
#pragma unroll 8
    for (int ks = 0; ks < 32; ++ks) {
      const int ke = ks * 32 + kc4 * 8;
      bf16x8 a1 = *(const bf16x8*)(a1p + ke);
      bf16x8 a2 = *(const bf16x8*)(a2p + ke);
      bf16x8 a3 = *(const bf16x8*)(a3p + ke);
#pragma unroll
      for (int nt = 0; nt < 2; ++nt) {
        const int r = nt ? (16 + (l15 & 7)) : l15;   // clamp pad rows -> valid
        const int off = r * 2048 + ((ks * 64 + kc4 * 16) ^ ((r & 7) << 4));
        bf16x8 b1 = *(const bf16x8*)((const char*)S + off);
        bf16x8 b2 = *(const bf16x8*)((const char*)S + 49152 + off);
        bf16x8 b3 = *(const bf16x8*)((const char*)S + 98304 + off);
        acc[nt] = __builtin_amdgcn_mfma_f32_16x16x32_bf16(a3, b1, acc[nt], 0, 0, 0);
        acc[nt] = __builtin_amdgcn_mfma_f32_16x16x32_bf16(a1, b3, acc[nt], 0, 0, 0);
        acc[nt] = __builtin_amdgcn_mfma_f32_16x16x32_bf16(a2, b2, acc[nt], 0, 0, 0);
        acc[nt] = __builtin_amdgcn_mfma_f32_16x16x32_bf16(a2, b1, acc[nt], 0, 0, 0);
        acc[nt] = __builtin_amdgcn_mfma_f32_16x16x32_bf16(a1, b2, acc[nt], 0, 0, 0);
        acc[nt] = __builtin_amdgcn_mfma_f32_16x16x32_bf16(a1, b1, acc[nt], 0, 0, 0);
      }
    }
    // C -> LDS scratch (cols 0..23 only)
#pragma unroll
    for (int j = 0; j < 4; ++j) {
      int row = w * 16 + q4 * 4 + j;
      Cg[row * 25 + l15] = acc[0][j];
      if (l15 < 8) Cg[row * 25 + 16 + l15] = acc[1][j];
    }
    __syncthreads();

    // ---- gate math for this thread's (i, j') ----
    {
      float v0 = Cg[gi_i * 25 + 0 + gj];
      float v1 = Cg[gi_i * 25 + 4 + gj];
      float v2 = Cg[gi_i * 25 + 8 + gj];
      float v3 = Cg[gi_i * 25 + 12 + gj];
      float v4 = Cg[gi_i * 25 + 16 + gj];
      float v5 = Cg[gi_i * 25 + 20 + gj];
      float gir = (t == 0) ? bi_r : (v0 + bi_r);
      float giz = (t == 0) ? bi_z : (v1 + bi_z);
      float gin = (t == 0) ? bi_n : (v2 + bi_n);
      float ghr = v3 + bh_r;
      float ghz = v4 + bh_z;
      float ghn = v5 + bh_n;
      float rr = 1.0f / (1.0f + expf(-(gir + ghr)));
      float zz = 1.0f / (1.0f + expf(-(giz + ghz)));
      float nn = tanhf(gin + rr * ghn);
      float hn2 = (1.0f - zz) * nn + zz * hreg;
      hreg = hn2;
      size_t o = ((size_t)t * BBATCH + gi_i) * HD + jglob;
      outs[o] = hn2;
      ushort a = f2bf_rne(hn2);
      outs_bf[o] = a;
      float r1 = hn2 - bf2f(a);
      ushort bb2 = f2bf_rne(r1);
      float r2 = r1 - bf2f(bb2);
      int idx = gi_i * HD + jglob;
      n1[idx] = a; n2[idx] = bb2; n3[idx] = f2bf_rne(r2);
    }
    if (t < TSTEP - 1) {
      __threadfence();
      grid_bar2(bar, GRUB / 8);
    }
  }
}

// ---------------- bf16 MFMA fc_out prefilter v5.1 ---------------------------
// grid (16 rb, 250 cb), XCD-pinned A. BK=64 double-buffer, counted vmcnt(8);
// epilogue L1 scan re-indexed conflict-free (banks rr*5 mod 32 all distinct).
__global__ __launch_bounds__(256) void gemm_out_mfma(
    const ushort* __restrict__ Abf, const ushort* __restrict__ Bbf,
    const float* __restrict__ b_out, u64* __restrict__ keys) {
  __shared__ ushort Sm[2][2][8192];   // [buf][A/B][128*64] = 64 KB
  float* Cs = (float*)&Sm[0][0][0];                   // 17 KB overlay
  u64* pkL1 = (u64*)((char*)&Sm[0][0][0] + 17024);    // 8 KB
  u64* pkL2 = pkL1 + 1024;                            // 2 KB

  const int tid = threadIdx.x;
  const int lane = tid & 63;
  const int wid = tid >> 6;
  const int wr = wid >> 1, wc = wid & 1;
  const int cb = blockIdx.y;
  const int n0 = cb * 128;
  const int r0 = blockIdx.x * 128;

  const ushort* Ag = Abf + (size_t)r0 * HD;
  const ushort* Bg = Bbf + (size_t)n0 * HD;
  const int rc = lane >> 3;
  const int gr8 = ((lane & 7) ^ rc) * 8;
  const int l15 = lane & 15;
  const int kseg = (lane >> 4) * 16;

#define STAGE_OUT(buf, kt) do {                                      \
    ushort* SA_ = &Sm[buf][0][0];                                    \
    ushort* SB_ = &Sm[buf][1][0];                                    \
    const int k0_ = (kt) * 64;                                       \
    _Pragma("unroll")                                                \
    for (int c_ = 0; c_ < 4; ++c_) {                                 \
      int ch_ = wid * 4 + c_;                                        \
      int row_ = ch_ * 8 + rc;                                       \
      gload16(Ag + (size_t)row_ * HD + k0_ + gr8, SA_ + ch_ * 512);  \
      gload16(Bg + (size_t)row_ * HD + k0_ + gr8, SB_ + ch_ * 512);  \
    }                                                                \
  } while (0)

#define COMPUTE_OUT(buf) do {                                        \
    const ushort* SA_ = &Sm[buf][0][0];                              \
    const ushort* SB_ = &Sm[buf][1][0];                              \
    _Pragma("unroll")                                                \
    for (int ks_ = 0; ks_ < 2; ++ks_) {                              \
      bf16x8 a_[4], b_[4];                                           \
      const int kb_ = ks_ * 64 + kseg;                               \
      _Pragma("unroll")                                              \
      for (int m_ = 0; m_ < 4; ++m_) {                               \
        int row_ = wr * 64 + m_ * 16 + l15;                          \
        int off_ = row_ * 128 + (kb_ ^ ((row_ & 7) << 4));           \
        a_[m_] = *(const bf16x8*)((const char*)SA_ + off_);          \
      }                                                              \
      _Pragma("unroll")                                              \
      for (int n_ = 0; n_ < 4; ++n_) {                               \
        int row_ = wc * 64 + n_ * 16 + l15;                          \
        int off_ = row_ * 128 + (kb_ ^ ((row_ & 7) << 4));           \
        b_[n_] = *(const bf16x8*)((const char*)SB_ + off_);          \
      }                                                              \
      _Pragma("unroll")                                              \
      for (int m_ = 0; m_ < 4; ++m_)                                 \
        _Pragma("unroll")                                            \
        for (int n_ = 0; n_ < 4; ++n_)                               \
          acc[m_][n_] = __builtin_amdgcn_mfma_f32_16x16x32_bf16(     \
              a_[m_], b_[n_], acc[m_][n_], 0, 0, 0);                 \
    }                                                                \
  } while (0)

  float bo[4];
#pragma unroll
  for (int n = 0; n < 4; ++n) bo[n] = b_out[n0 + wc * 64 + n * 16 + l15];

  f32x4 acc[4][4];
#pragma unroll
  for (int m = 0; m < 4; ++m)
#pragma unroll
    for (int n = 0; n < 4; ++n) acc[m][n] = (f32x4){0.f, 0.f, 0.f, 0.f};

  STAGE_OUT(0, 0);
  int p = 0;
  for (int kt = 0; kt < 16; ++kt) {
    if (kt < 15) {
      STAGE_OUT(p ^ 1, kt + 1);
      asm volatile("s_waitcnt vmcnt(8)" ::: "memory");
    } else {
      asm volatile("s_waitcnt vmcnt(0)" ::: "memory");
    }
    __builtin_amdgcn_s_barrier();
    __builtin_amdgcn_sched_barrier(0);
    COMPUTE_OUT(p);
    __builtin_amdgcn_sched_barrier(0);
    __builtin_amdgcn_s_barrier();
    p ^= 1;
  }
  __syncthreads();

#pragma unroll
  for (int q = 0; q < 4; ++q) {
    if (wr == (q >> 1)) {
#pragma unroll
      for (int mi = 0; mi < 2; ++mi) {
        const int m = (q & 1) * 2 + mi;
#pragma unroll
        for (int n = 0; n < 4; ++n) {
          int c = wc * 64 + n * 16 + l15;
#pragma unroll
          for (int j = 0; j < 4; ++j) {
            int lr = mi * 16 + (lane >> 4) * 4 + j;
            Cs[lr * 133 + c] = acc[m][n][j] + bo[n];
          }
        }
      }
    }
    __syncthreads();
    {  // level 1: rr = tid&31 -> per-wave banks rr*5 mod 32 all distinct
      int rr = tid & 31, seg = tid >> 5;
      const float* rp = Cs + rr * 133 + seg * 16;
      u64 t4[4] = {0, 0, 0, 0};
#pragma unroll
      for (int c = 0; c < 16; ++c) insert4(t4, packkey(rp[c], n0 + seg * 16 + c));
      u64* d = pkL1 + (rr * 8 + seg) * 4;
      d[0] = t4[0]; d[1] = t4[1]; d[2] = t4[2]; d[3] = t4[3];
    }
    __syncthreads();
    if (tid < 64) {
      int rr = tid >> 1, hf = tid & 1;
      const u64* s = pkL1 + (rr * 8 + hf * 4) * 4;
      u64 t4[4] = {s[0], s[1], s[2], s[3]};
#pragma unroll
      for (int e = 4; e < 16; ++e) insert4(t4, s[e]);
      u64* d = pkL2 + tid * 4;
      d[0] = t4[0]; d[1] = t4[1]; d[2] = t4[2]; d[3] = t4[3];
    }
    __syncthreads();
    if (tid < 32) {
      const u64* s = pkL2 + tid * 8;
      u64 t4[4] = {s[0], s[1], s[2], s[3]};
      insert4(t4, s[4]); insert4(t4, s[5]); insert4(t4, s[6]); insert4(t4, s[7]);
      int grow = r0 + q * 32 + tid;
      u64* kp2 = keys + ((size_t)grow * NCB + cb) * 4;
      kp2[0] = t4[0]; kp2[1] = t4[1]; kp2[2] = t4[2]; kp2[3] = t4[3];
    }
    __syncthreads();
  }
#undef STAGE_OUT
#undef COMPUTE_OUT
}

// ---------------- per-row merge v2: 1 wave, reg-resident, no barriers ------
__global__ __launch_bounds__(64) void merge_sample2(
    const u64* __restrict__ keys, const float* __restrict__ outs,
    const float* __restrict__ W_out, const float* __restrict__ b_out,
    int* __restrict__ out) {
  const int r = blockIdx.x;
  const int lane = threadIdx.x;
  __shared__ float row_f[1024];
  {
    const float4* src = (const float4*)(outs + (size_t)r * HD);
    float4* dst = (float4*)row_f;
#pragma unroll
    for (int m = 0; m < 4; ++m) dst[lane + m * 64] = src[lane + m * 64];
  }
  u64 t8[8] = {0, 0, 0, 0, 0, 0, 0, 0};
  const u64* KR = keys + (size_t)r * 1000;
#pragma unroll
  for (int m = 0; m < 16; ++m) {
    int i = lane + (m << 6);
    if (i < 1000) {
      u64 k = KR[i];
      if (k > t8[7]) {
        t8[7] = k;
#pragma unroll
        for (int e = 7; e > 0; --e) {
          u64 hi = t8[e - 1], lo = t8[e];
          t8[e - 1] = (lo > hi) ? lo : hi;
          t8[e]     = (lo > hi) ? hi : lo;
        }
      }
    }
  }
  const int mycand = lane >> 2;
  u64 myw = 0;
#pragma unroll
  for (int it = 0; it < NCAND; ++it) {
    u64 bmax = t8[0];
#pragma unroll
    for (int o = 32; o; o >>= 1) {
      u64 x = __shfl_xor(bmax, o);
      if (x > bmax) bmax = x;
    }
    if (it == mycand) myw = bmax;
    if (t8[0] == bmax) {
#pragma unroll
      for (int e = 0; e < 7; ++e) t8[e] = t8[e + 1];
      t8[7] = 0;
    }
  }
  const int myvi = (int)(~(u32)(myw & 0xffffffffu));
  float mysum;
  {
    const float4* wrow = (const float4*)(W_out + (size_t)myvi * HD);
    const float4* rf = (const float4*)row_f;
    const int q = lane & 3;
    float s = 0.f;
#pragma unroll
    for (int m2 = 0; m2 < 64; ++m2) {
      float4 a = rf[q + m2 * 4];
      float4 bb = wrow[q + m2 * 4];
      s += a.x * bb.x; s += a.y * bb.y; s += a.z * bb.z; s += a.w * bb.w;
    }
    s += __shfl_xor(s, 1);
    s += __shfl_xor(s, 2);
    mysum = s + b_out[myvi];
  }
  float v[NCAND]; int vi[NCAND];
#pragma unroll
  for (int c = 0; c < NCAND; ++c) {
    v[c] = __shfl(mysum, c * 4);
    vi[c] = __shfl(myvi, c * 4);
  }
  if (lane == 0) {
#pragma unroll
    for (int a = 0; a < 8; ++a)
#pragma unroll
      for (int b2 = a + 1; b2 < NCAND; ++b2) {
        bool sw = (v[b2] > v[a]) || (v[b2] == v[a] && vi[b2] < vi[a]);
        if (sw) {
          float tf = v[a]; v[a] = v[b2]; v[b2] = tf;
          int ti = vi[a]; vi[a] = vi[b2]; vi[b2] = ti;
        }
      }
    const float M = v[0];
    const float TINY = 1.17549435e-38f;
    float best = -3.4e38f; int bi = 0;
#pragma unroll
    for (int k = 0; k < 8; ++k) {
      float lp = v[k] - M;
      u32 bits = jax_random_bits((u32)(r * 8 + k));
      float f = __uint_as_float((bits >> 9) | 0x3f800000u) - 1.0f;
      float u = f * (1.0f - TINY) + TINY;
      u = fmaxf(TINY, u);
      float g = -logf(-logf(u));
      float s = g + lp;
      if (s > best) { best = s; bi = k; }
    }
    int t = r >> 6, b = r & 63;
    out[b * TSTEP + t] = vi[bi];
  }
}

extern "C" void kernel_launch(void* const* d_in, const int* in_sizes, int n_in,
                              void* d_out, int out_size, void* d_ws, size_t ws_size,
                              hipStream_t stream) {
  (void)in_sizes; (void)n_in; (void)out_size; (void)ws_size;
  const float* vectors = (const float*)d_in[0];
  const float* W_fc_in = (const float*)d_in[1];
  const float* b_fc_in = (const float*)d_in[2];
  const float* W_ih    = (const float*)d_in[3];
  const float* W_hh    = (const float*)d_in[4];
  const float* b_ih    = (const float*)d_in[5];
  const float* b_hh    = (const float*)d_in[6];
  const float* W_out   = (const float*)d_in[7];
  const float* b_out   = (const float*)d_in[8];
  int* out = (int*)d_out;

  char* w = (char*)d_ws;
  float* h = (float*)w;          w += (size_t)BBATCH * HD * 4;        // 256 KB
  float* outs = (float*)w;       w += (size_t)NROWS * HD * 4;         // 8 MB
  ushort* outs_bf = (ushort*)w;  w += (size_t)NROWS * HD * 2;         // 4 MB
  ushort* Wbf = (ushort*)w;      w += (size_t)VOCAB * HD * 2;         // 65.5 MB
  // X region: permuted Wg splits live through the GRU; keys aliases after.
  char* X = w;                   w += (size_t)3 * GATE6 * HD * 2;     // 37.75 MB
  ushort* Wg1 = (ushort*)X;
  ushort* Wg2 = Wg1 + (size_t)GATE6 * HD;
  ushort* Wg3 = Wg2 + (size_t)GATE6 * HD;
  u64* keys = (u64*)X;                                               // alias
  ushort* hA1 = (ushort*)w;      w += (size_t)BBATCH * HD * 2;        // 128 KB
  ushort* hA2 = (ushort*)w;      w += (size_t)BBATCH * HD * 2;
  ushort* hA3 = (ushort*)w;      w += (size_t)BBATCH * HD * 2;
  ushort* hB1 = (ushort*)w;      w += (size_t)BBATCH * HD * 2;
  ushort* hB2 = (ushort*)w;      w += (size_t)BBATCH * HD * 2;
  ushort* hB3 = (ushort*)w;      w += (size_t)BBATCH * HD * 2;
  u32* bar = (u32*)w;            w += 4096;
  float* part = (float*)w;       // fc_in partials: 4*64*1024 fp32 = 1 MB

  hipMemsetAsync(bar, 0, 4096, stream);

  // one-time weight conversions
  tobf16<<<4096, 256, 0, stream>>>(W_out, Wbf, VOCAB * HD / 8);
  tobf16x3_gruP24<<<GATE6 * (HD / 8) / 256, 256, 0, stream>>>(W_ih, W_hh,
                                                              Wg1, Wg2, Wg3);

  // fc_in: h0 = vectors @ W_fc_in^T + b_fc_in  (fp32, split-K=4)
  gemm64_nt<<<dim3(32, 4), 256, 0, stream>>>(vectors, W_fc_in, part);
  combine_fcin<<<256, 256, 0, stream>>>(part, b_fc_in, h, hA1, hA2, hA3);

  // all 32 GRU steps: persistent, W' LDS-resident, ping-pong h-splits
  gru_all<<<GRUB, 256, 0, stream>>>(Wg1, Wg2, Wg3, b_ih, b_hh, h,
                                    outs, outs_bf, hA1, hA2, hA3,
                                    hB1, hB2, hB3, bar);

  // bf16 MFMA prefilter over the vocab
  gemm_out_mfma<<<dim3(16, NCB), 256, 0, stream>>>(outs_bf, Wbf, b_out, keys);

  // per-row top-16 select + exact fp32 rescore + Threefry/Gumbel sampling
  merge_sample2<<<NROWS, 64, 0, stream>>>(keys, outs, W_out, b_out, out);
}

// Round 11
// 1023.288 us; speedup vs baseline: 2.4600x; 2.4600x over previous
//
#include <hip/hip_runtime.h>
#include <stdint.h>

typedef unsigned int u32;
typedef unsigned long long u64;
typedef unsigned short ushort;
typedef signed char i8;
typedef __attribute__((ext_vector_type(8))) short bf16x8;
typedef __attribute__((ext_vector_type(4))) float f32x4;
typedef __attribute__((ext_vector_type(4))) int i32x4;

#define JAX_PARTITIONABLE 1

#define HD     1024
#define BBATCH 64
#define TSTEP  32
#define VOCAB  32000
#define NROWS  2048      // TSTEP * BBATCH
#define GATE6  6144      // 6 * HD
#define NCB    250       // 32000 / 128 col-blocks
#define NCAND  16

// ---------------- Threefry-2x32 (matches jax._src.prng) ----------------
__device__ __forceinline__ void threefry2x32(u32 k0, u32 k1, u32 x0, u32 x1,
                                             u32& y0, u32& y1) {
  u32 ks2 = k0 ^ k1 ^ 0x1BD11BDAu;
  x0 += k0; x1 += k1;
#define TFR(r) do { x0 += x1; x1 = (x1 << (r)) | (x1 >> (32 - (r))); x1 ^= x0; } while (0)
  TFR(13); TFR(15); TFR(26); TFR(6);   x0 += k1;  x1 += ks2 + 1u;
  TFR(17); TFR(29); TFR(16); TFR(24);  x0 += ks2; x1 += k0 + 2u;
  TFR(13); TFR(15); TFR(26); TFR(6);   x0 += k0;  x1 += k1 + 3u;
  TFR(17); TFR(29); TFR(16); TFR(24);  x0 += k1;  x1 += ks2 + 4u;
  TFR(13); TFR(15); TFR(26); TFR(6);   x0 += ks2; x1 += k0 + 5u;
#undef TFR
  y0 = x0; y1 = x1;
}

__device__ __forceinline__ u32 jax_random_bits(u32 n) {
#if JAX_PARTITIONABLE
  u32 y0, y1; threefry2x32(0u, 42u, 0u, n, y0, y1);
  return y0 ^ y1;
#else
  u32 y0, y1;
  if (n < 8192u) { threefry2x32(0u, 42u, n, n + 8192u, y0, y1); return y0; }
  else           { threefry2x32(0u, 42u, n - 8192u, n, y0, y1); return y1; }
#endif
}

// value-desc, tie -> lower vocab index wins
__device__ __forceinline__ u64 packkey(float v, int idx) {
  u32 b = __float_as_uint(v);
  b = (b & 0x80000000u) ? ~b : (b | 0x80000000u);
  return ((u64)b << 32) | (u64)(~(u32)idx);
}

__device__ __forceinline__ void insert4(u64* t4, u64 k) {
  if (k > t4[3]) {
    t4[3] = k;
    if (t4[3] > t4[2]) { u64 tm = t4[2]; t4[2] = t4[3]; t4[3] = tm; }
    if (t4[2] > t4[1]) { u64 tm = t4[1]; t4[1] = t4[2]; t4[2] = tm; }
    if (t4[1] > t4[0]) { u64 tm = t4[0]; t4[0] = t4[1]; t4[1] = tm; }
  }
}

__device__ __forceinline__ ushort f2bf_rne(float x) {
  u32 u = __float_as_uint(x);
  return (ushort)((u + 0x7fffu + ((u >> 16) & 1u)) >> 16);
}
__device__ __forceinline__ float bf2f(ushort h) {
  return __uint_as_float(((u32)h) << 16);
}

typedef const __attribute__((address_space(1))) void* gas_ptr;
typedef __attribute__((address_space(3))) void* las_ptr;
__device__ __forceinline__ void gload16(const void* g, void* l) {
  __builtin_amdgcn_global_load_lds((gas_ptr)g, (las_ptr)l, 16, 0, 0);
}

// ---------------- fp32 -> bf16 bulk convert ----------------
__global__ __launch_bounds__(256) void tobf16(const float* __restrict__ src,
                                              ushort* __restrict__ dst, int n8) {
  int i = blockIdx.x * 256 + threadIdx.x;
  const int stride = gridDim.x * 256;
  for (; i < n8; i += stride) {
    const float4* s4 = (const float4*)src + (size_t)i * 2;
    float4 a = s4[0], b = s4[1];
    u32 o0 = f2bf_rne(a.x) | ((u32)f2bf_rne(a.y) << 16);
    u32 o1 = f2bf_rne(a.z) | ((u32)f2bf_rne(a.w) << 16);
    u32 o2 = f2bf_rne(b.x) | ((u32)f2bf_rne(b.y) << 16);
    u32 o3 = f2bf_rne(b.z) | ((u32)f2bf_rne(b.w) << 16);
    ((uint4*)dst)[i] = make_uint4(o0, o1, o2, o3);
  }
}

// ------- W_ih|W_hh -> PERMUTED int8 4-level fixed-point planes -------------
// out row r' = b*48 + g*8 + j'  (b=0..127, g=0..5, j'=0..7).
// W = q1*2^-11 + q2*2^-18 + q3*2^-25 + q4*2^-32 + eps, |eps| <= 2^-33.
__global__ __launch_bounds__(256) void quantW_i8(
    const float* __restrict__ Wih, const float* __restrict__ Whh,
    i8* __restrict__ wq) {
  int i = blockIdx.x * 256 + threadIdx.x;
  if (i >= GATE6 * (HD / 8)) return;
  const size_t WP = (size_t)GATE6 * HD;
  int rp = i >> 7;           // out row
  int kc = i & 127;          // 8-elem chunk along K
  int b = rp / 48, rem = rp % 48;
  int g = rem >> 3, jp = rem & 7;
  const float* src = (g < 3)
      ? (Wih + ((size_t)g * HD + b * 8 + jp) * HD)
      : (Whh + ((size_t)(g - 3) * HD + b * 8 + jp) * HD);
  const float4* s4 = (const float4*)(src + kc * 8);
  float v[8];
  float4 a = s4[0], bb = s4[1];
  v[0]=a.x; v[1]=a.y; v[2]=a.z; v[3]=a.w; v[4]=bb.x; v[5]=bb.y; v[6]=bb.z; v[7]=bb.w;
  u64 p[4] = {0, 0, 0, 0};
#pragma unroll
  for (int e = 0; e < 8; ++e) {
    float w0 = v[e];
    float q1 = rintf(w0 * 0x1p11f);
    float r1 = w0 - q1 * 0x1p-11f;
    float q2 = rintf(r1 * 0x1p18f);
    float r2 = r1 - q2 * 0x1p-18f;
    float q3 = rintf(r2 * 0x1p25f);
    float r3 = r2 - q3 * 0x1p-25f;
    float q4 = rintf(r3 * 0x1p32f);
    p[0] |= (u64)(u32)((int)q1 & 0xff) << (8 * e);
    p[1] |= (u64)(u32)((int)q2 & 0xff) << (8 * e);
    p[2] |= (u64)(u32)((int)q3 & 0xff) << (8 * e);
    p[3] |= (u64)(u32)((int)q4 & 0xff) << (8 * e);
  }
  size_t off = (size_t)rp * HD + kc * 8;
#pragma unroll
  for (int lv = 0; lv < 4; ++lv)
    *(u64*)(wq + lv * WP + off) = p[lv];
}

// ---------------- fc_in skinny NT GEMM (fp32, one-time) ----------------
__global__ __launch_bounds__(256) void gemm64_nt(
    const float* __restrict__ A, const float* __restrict__ B,
    float* __restrict__ part) {
  __shared__ float4 As4[64 * 33];
  __shared__ float4 Bs4[32 * 33];
  const int tid = threadIdx.x;
  const int n0 = blockIdx.x * 32;
  const float* Brow = B + (size_t)n0 * HD;
  const int ks = blockIdx.y * 256;
  const int tc = tid & 7, trg = tid >> 3;
  float acc[2][4] = {};
  for (int kc = 0; kc < 2; ++kc) {
    const int k0 = ks + kc * 128;
#pragma unroll
    for (int l = 0; l < 8; ++l) {
      int m = tid + l * 256; int row = m >> 5, k4 = m & 31;
      As4[row * 33 + k4] = *(const float4*)(A + (size_t)row * HD + k0 + k4 * 4);
    }
#pragma unroll
    for (int l = 0; l < 4; ++l) {
      int m = tid + l * 256; int row = m >> 5, k4 = m & 31;
      Bs4[row * 33 + k4] = *(const float4*)(Brow + (size_t)row * HD + k0 + k4 * 4);
    }
    __syncthreads();
#pragma unroll
    for (int kq = 0; kq < 32; ++kq) {
      float4 av[2], bv[4];
      av[0] = As4[trg * 33 + kq];
      av[1] = As4[(trg + 32) * 33 + kq];
      bv[0] = Bs4[tc * 33 + kq];
      bv[1] = Bs4[(tc + 8) * 33 + kq];
      bv[2] = Bs4[(tc + 16) * 33 + kq];
      bv[3] = Bs4[(tc + 24) * 33 + kq];
#pragma unroll
      for (int i = 0; i < 2; ++i)
#pragma unroll
        for (int j = 0; j < 4; ++j) {
          acc[i][j] += av[i].x * bv[j].x;
          acc[i][j] += av[i].y * bv[j].y;
          acc[i][j] += av[i].z * bv[j].z;
          acc[i][j] += av[i].w * bv[j].w;
        }
    }
    __syncthreads();
  }
  float* P = part + (size_t)blockIdx.y * BBATCH * HD;
#pragma unroll
  for (int i = 0; i < 2; ++i) {
    int b = trg + 32 * i;
#pragma unroll
    for (int j = 0; j < 4; ++j)
      P[(size_t)b * HD + n0 + tc + 8 * j] = acc[i][j];
  }
}

// ---- h -> 4-level int8 planes (shifts 5,12,19,26; |eps| <= 2^-27) ----
__device__ __forceinline__ void quant_h(float hv, i8* q) {
  float q1 = rintf(hv * 0x1p5f);
  q1 = fminf(fmaxf(q1, -127.f), 127.f);
  float r1 = hv - q1 * 0x1p-5f;
  float q2 = rintf(r1 * 0x1p12f);
  float r2 = r1 - q2 * 0x1p-12f;
  float q3 = rintf(r2 * 0x1p19f);
  float r3 = r2 - q3 * 0x1p-19f;
  float q4 = rintf(r3 * 0x1p26f);
  q[0] = (i8)(int)q1; q[1] = (i8)(int)q2; q[2] = (i8)(int)q3; q[3] = (i8)(int)q4;
}

// ---------------- fc_in combine (+ 4-level i8 quant of h0) ----------------
__global__ __launch_bounds__(256) void combine_fcin(
    const float* __restrict__ part, const float* __restrict__ b_fc,
    float* __restrict__ h, i8* __restrict__ hq) {
  int idx = blockIdx.x * 256 + threadIdx.x;
  int j = idx & 1023; int b = idx >> 10;
  const size_t S = (size_t)BBATCH * HD;
  const float* p = part + (size_t)b * HD;
  float d = p[j]; d += p[S + j]; d += p[2 * S + j]; d += p[3 * S + j];
  float hv = d + b_fc[j];
  h[idx] = hv;
  i8 q[4]; quant_h(hv, q);
  const size_t HP = (size_t)BBATCH * HD;
  hq[idx] = q[0]; hq[HP + idx] = q[1]; hq[2 * HP + idx] = q[2]; hq[3 * HP + idx] = q[3];
}

// ---------------- GRU one step: exact-int8 MFMA, no LDS, no staging --------
// 256 blocks (hb-pair XCD co-located: bid=16*(b/8)+(b%8)+8*hb); 128 thr = 2
// waves; block = (jslice b of 8 cols, batch half hb). W' i8 planes (25.2 MB,
// 3.15 MB/XCD) read straight from L2/L3; h planes ping-pong (no race).
// 13 products (h-shift a in {5,12,19,26} x W-shift b in {11,18,25,32},
// a+b <= 44) into 6 scale-grouped exact i32 accumulators.
__global__ __launch_bounds__(128) void gru_step(
    const i8* __restrict__ Wq, const float* __restrict__ b_ih,
    const float* __restrict__ b_hh, float* __restrict__ h,
    float* __restrict__ outs, ushort* __restrict__ outs_bf,
    const i8* __restrict__ hin, i8* __restrict__ hout, int t) {
  const int tid = threadIdx.x;
  const int lane = tid & 63, w = tid >> 6;
  const int grp = blockIdx.x >> 4;
  const int rmd = blockIdx.x & 15;
  const int hb = rmd >> 3;
  const int b = grp * 8 + (rmd & 7);
  const int l15 = lane & 15, kc4 = lane >> 4;
  const int arow = hb * 32 + w * 16 + l15;

  const size_t WP = (size_t)GATE6 * HD;
  const size_t HP = (size_t)BBATCH * HD;
  const i8* Wb = Wq + (size_t)b * 48 * HD;
  const i8* hrow = hin + (size_t)arow * HD;

  i32x4 acc[6][3];
#pragma unroll
  for (int g = 0; g < 6; ++g)
#pragma unroll
    for (int nt = 0; nt < 3; ++nt) acc[g][nt] = (i32x4){0, 0, 0, 0};

#pragma unroll 4
  for (int kt = 0; kt < 16; ++kt) {
    const int ko = kt * 64 + kc4 * 16;
    i32x4 ha[4];
#pragma unroll
    for (int lv = 0; lv < 4; ++lv)
      ha[lv] = *(const i32x4*)(hrow + lv * HP + ko);
    i32x4 wb[4][3];
#pragma unroll
    for (int lv = 0; lv < 4; ++lv)
#pragma unroll
      for (int nt = 0; nt < 3; ++nt)
        wb[lv][nt] = *(const i32x4*)(Wb + lv * WP + (size_t)(nt * 16 + l15) * HD + ko);
#pragma unroll
    for (int nt = 0; nt < 3; ++nt) {
      acc[0][nt] = __builtin_amdgcn_mfma_i32_16x16x64_i8(ha[0], wb[0][nt], acc[0][nt], 0, 0, 0); // s=16
      acc[1][nt] = __builtin_amdgcn_mfma_i32_16x16x64_i8(ha[0], wb[1][nt], acc[1][nt], 0, 0, 0); // s=23
      acc[2][nt] = __builtin_amdgcn_mfma_i32_16x16x64_i8(ha[1], wb[0][nt], acc[2][nt], 0, 0, 0); // s=23
      acc[3][nt] = __builtin_amdgcn_mfma_i32_16x16x64_i8(ha[0], wb[2][nt], acc[3][nt], 0, 0, 0); // s=30
      acc[3][nt] = __builtin_amdgcn_mfma_i32_16x16x64_i8(ha[1], wb[1][nt], acc[3][nt], 0, 0, 0);
      acc[3][nt] = __builtin_amdgcn_mfma_i32_16x16x64_i8(ha[2], wb[0][nt], acc[3][nt], 0, 0, 0);
      acc[4][nt] = __builtin_amdgcn_mfma_i32_16x16x64_i8(ha[0], wb[3][nt], acc[4][nt], 0, 0, 0); // s=37
      acc[4][nt] = __builtin_amdgcn_mfma_i32_16x16x64_i8(ha[1], wb[2][nt], acc[4][nt], 0, 0, 0);
      acc[4][nt] = __builtin_amdgcn_mfma_i32_16x16x64_i8(ha[2], wb[1][nt], acc[4][nt], 0, 0, 0);
      acc[4][nt] = __builtin_amdgcn_mfma_i32_16x16x64_i8(ha[3], wb[0][nt], acc[4][nt], 0, 0, 0);
      acc[5][nt] = __builtin_amdgcn_mfma_i32_16x16x64_i8(ha[1], wb[3][nt], acc[5][nt], 0, 0, 0); // s=44
      acc[5][nt] = __builtin_amdgcn_mfma_i32_16x16x64_i8(ha[2], wb[2][nt], acc[5][nt], 0, 0, 0);
      acc[5][nt] = __builtin_amdgcn_mfma_i32_16x16x64_i8(ha[3], wb[1][nt], acc[5][nt], 0, 0, 0);
    }
  }

  // ---- combine (smallest scale first; deterministic) + gate math ----
  const bool low = (l15 < 8);
  const int j = b * 8 + l15;
  float bi_r = 0.f, bi_z = 0.f, bi_n = 0.f, bh_r = 0.f, bh_z = 0.f, bh_n = 0.f;
  if (low) {
    bi_r = b_ih[j]; bi_z = b_ih[HD + j]; bi_n = b_ih[2 * HD + j];
    bh_r = b_hh[j]; bh_z = b_hh[HD + j]; bh_n = b_hh[2 * HD + j];
  }
#pragma unroll
  for (int r = 0; r < 4; ++r) {
    float c[3];
#pragma unroll
    for (int nt = 0; nt < 3; ++nt) {
      float v = (float)acc[5][nt][r] * 0x1p-44f;
      v += (float)acc[4][nt][r] * 0x1p-37f;
      v += (float)acc[3][nt][r] * 0x1p-30f;
      v += (float)acc[2][nt][r] * 0x1p-23f;
      v += (float)acc[1][nt][r] * 0x1p-23f;
      v += (float)acc[0][nt][r] * 0x1p-16f;
      c[nt] = v;
    }
    float p0 = __shfl_xor(c[0], 8);    // iz  (on low lanes)
    float p1 = __shfl_xor(c[1], 8);    // hr
    float p2 = __shfl_xor(c[2], 8);    // hn
    if (low) {
      float gir = (t == 0) ? bi_r : (c[0] + bi_r);
      float giz = (t == 0) ? bi_z : (p0 + bi_z);
      float gin = (t == 0) ? bi_n : (c[1] + bi_n);
      float ghr = p1 + bh_r;
      float ghz = c[2] + bh_z;
      float ghn = p2 + bh_n;
      float rr = 1.0f / (1.0f + expf(-(gir + ghr)));
      float zz = 1.0f / (1.0f + expf(-(giz + ghz)));
      float nn = tanhf(gin + rr * ghn);
      int i = hb * 32 + w * 16 + kc4 * 4 + r;
      int idx = i * HD + j;
      float hp = h[idx];
      float hn2 = (1.0f - zz) * nn + zz * hp;
      h[idx] = hn2;
      size_t o = ((size_t)t * BBATCH + i) * HD + j;
      outs[o] = hn2;
      outs_bf[o] = f2bf_rne(hn2);
      i8 q[4]; quant_h(hn2, q);
      hout[idx] = q[0]; hout[HP + idx] = q[1];
      hout[2 * HP + idx] = q[2]; hout[3 * HP + idx] = q[3];
    }
  }
}

// ---------------- bf16 MFMA fc_out prefilter v6 ----------------------------
// grid (8, 500): xcd = cb%8 (each XCD owns its vocab slice; W fetched from
// HBM once overall), rb-fastest within XCD so 16 rb-blocks share each W slice
// via L2. BK=64 double-buffer, counted vmcnt(8); epilogue overlaid on staging.
__global__ __launch_bounds__(256) void gemm_out_mfma(
    const ushort* __restrict__ Abf, const ushort* __restrict__ Bbf,
    const float* __restrict__ b_out, u64* __restrict__ keys) {
  __shared__ ushort Sm[2][2][8192];   // [buf][A/B][128*64] = 64 KB
  float* Cs = (float*)&Sm[0][0][0];                   // 17 KB overlay
  u64* pkL1 = (u64*)((char*)&Sm[0][0][0] + 17024);    // 8 KB
  u64* pkL2 = pkL1 + 1024;                            // 2 KB

  const int tid = threadIdx.x;
  const int lane = tid & 63;
  const int wid = tid >> 6;
  const int wr = wid >> 1, wc = wid & 1;

  // decode (cb, rb) with xcd = cb%8 and rb-fastest order, 24-slot spillover
  int X = blockIdx.x, K = blockIdx.y;
  if (X >= 2 && K >= 496) { int e = (X - 2) * 4 + (K - 496); X = e / 12; K = 500 + e % 12; }
  const int cb = (K >> 4) * 8 + X;
  const int rb = K & 15;
  const int n0 = cb * 128;
  const int r0 = rb * 128;

  const ushort* Ag = Abf + (size_t)r0 * HD;
  const ushort* Bg = Bbf + (size_t)n0 * HD;
  const int rc = lane >> 3;
  const int gr8 = ((lane & 7) ^ rc) * 8;
  const int l15 = lane & 15;
  const int kseg = (lane >> 4) * 16;

#define STAGE_OUT(buf, kt) do {                                      \
    ushort* SA_ = &Sm[buf][0][0];                                    \
    ushort* SB_ = &Sm[buf][1][0];                                    \
    const int k0_ = (kt) * 64;                                       \
    _Pragma("unroll")                                                \
    for (int c_ = 0; c_ < 4; ++c_) {                                 \
      int ch_ = wid * 4 + c_;                                        \
      int row_ = ch_ * 8 + rc;                                       \
      gload16(Ag + (size_t)row_ * HD + k0_ + gr8, SA_ + ch_ * 512);  \
      gload16(Bg + (size_t)row_ * HD + k0_ + gr8, SB_ + ch_ * 512);  \
    }                                                                \
  } while (0)

#define COMPUTE_OUT(buf) do {                                        \
    const ushort* SA_ = &Sm[buf][0][0];                              \
    const ushort* SB_ = &Sm[buf][1][0];                              \
    _Pragma("unroll")                                                \
    for (int ks_ = 0; ks_ < 2; ++ks_) {                              \
      bf16x8 a_[4], b_[4];                                           \
      const int kb_ = ks_ * 64 + kseg;                               \
      _Pragma("unroll")                                              \
      for (int m_ = 0; m_ < 4; ++m_) {                               \
        int row_ = wr * 64 + m_ * 16 + l15;                          \
        int off_ = row_ * 128 + (kb_ ^ ((row_ & 7) << 4));           \
        a_[m_] = *(const bf16x8*)((const char*)SA_ + off_);          \
      }                                                              \
      _Pragma("unroll")                                              \
      for (int n_ = 0; n_ < 4; ++n_) {                               \
        int row_ = wc * 64 + n_ * 16 + l15;                          \
        int off_ = row_ * 128 + (kb_ ^ ((row_ & 7) << 4));           \
        b_[n_] = *(const bf16x8*)((const char*)SB_ + off_);          \
      }                                                              \
      _Pragma("unroll")                                              \
      for (int m_ = 0; m_ < 4; ++m_)                                 \
        _Pragma("unroll")                                            \
        for (int n_ = 0; n_ < 4; ++n_)                               \
          acc[m_][n_] = __builtin_amdgcn_mfma_f32_16x16x32_bf16(     \
              a_[m_], b_[n_], acc[m_][n_], 0, 0, 0);                 \
    }                                                                \
  } while (0)

  float bo[4];
#pragma unroll
  for (int n = 0; n < 4; ++n) bo[n] = b_out[n0 + wc * 64 + n * 16 + l15];

  f32x4 acc[4][4];
#pragma unroll
  for (int m = 0; m < 4; ++m)
#pragma unroll
    for (int n = 0; n < 4; ++n) acc[m][n] = (f32x4){0.f, 0.f, 0.f, 0.f};

  STAGE_OUT(0, 0);
  int p = 0;
  for (int kt = 0; kt < 16; ++kt) {
    if (kt < 15) {
      STAGE_OUT(p ^ 1, kt + 1);
      asm volatile("s_waitcnt vmcnt(8)" ::: "memory");
    } else {
      asm volatile("s_waitcnt vmcnt(0)" ::: "memory");
    }
    __builtin_amdgcn_s_barrier();
    __builtin_amdgcn_sched_barrier(0);
    COMPUTE_OUT(p);
    __builtin_amdgcn_sched_barrier(0);
    __builtin_amdgcn_s_barrier();
    p ^= 1;
  }
  __syncthreads();

#pragma unroll
  for (int q = 0; q < 4; ++q) {
    if (wr == (q >> 1)) {
#pragma unroll
      for (int mi = 0; mi < 2; ++mi) {
        const int m = (q & 1) * 2 + mi;
#pragma unroll
        for (int n = 0; n < 4; ++n) {
          int c = wc * 64 + n * 16 + l15;
#pragma unroll
          for (int j = 0; j < 4; ++j) {
            int lr = mi * 16 + (lane >> 4) * 4 + j;
            Cs[lr * 133 + c] = acc[m][n][j] + bo[n];
          }
        }
      }
    }
    __syncthreads();
    {  // level 1: 256 threads, 16 cols each
      int rr = tid & 31, seg = tid >> 5;
      const float* rp = Cs + rr * 133 + seg * 16;
      u64 t4[4] = {0, 0, 0, 0};
#pragma unroll
      for (int c = 0; c < 16; ++c) insert4(t4, packkey(rp[c], n0 + seg * 16 + c));
      u64* d = pkL1 + (rr * 8 + seg) * 4;
      d[0] = t4[0]; d[1] = t4[1]; d[2] = t4[2]; d[3] = t4[3];
    }
    __syncthreads();
    if (tid < 64) {
      int rr = tid >> 1, hf = tid & 1;
      const u64* s = pkL1 + (rr * 8 + hf * 4) * 4;
      u64 t4[4] = {s[0], s[1], s[2], s[3]};
#pragma unroll
      for (int e = 4; e < 16; ++e) insert4(t4, s[e]);
      u64* d = pkL2 + tid * 4;
      d[0] = t4[0]; d[1] = t4[1]; d[2] = t4[2]; d[3] = t4[3];
    }
    __syncthreads();
    if (tid < 32) {
      const u64* s = pkL2 + tid * 8;
      u64 t4[4] = {s[0], s[1], s[2], s[3]};
      insert4(t4, s[4]); insert4(t4, s[5]); insert4(t4, s[6]); insert4(t4, s[7]);
      int grow = r0 + q * 32 + tid;
      u64* kp2 = keys + ((size_t)grow * NCB + cb) * 4;
      kp2[0] = t4[0]; kp2[1] = t4[1]; kp2[2] = t4[2]; kp2[3] = t4[3];
    }
    __syncthreads();
  }
#undef STAGE_OUT
#undef COMPUTE_OUT
}

// ---------------- per-row merge: 1 wave, reg-resident, no barriers ---------
__global__ __launch_bounds__(64) void merge_sample2(
    const u64* __restrict__ keys, const float* __restrict__ outs,
    const float* __restrict__ W_out, const float* __restrict__ b_out,
    int* __restrict__ out) {
  const int r = blockIdx.x;
  const int lane = threadIdx.x;
  __shared__ float row_f[1024];
  {
    const float4* src = (const float4*)(outs + (size_t)r * HD);
    float4* dst = (float4*)row_f;
#pragma unroll
    for (int m = 0; m < 4; ++m) dst[lane + m * 64] = src[lane + m * 64];
  }
  u64 t8[8] = {0, 0, 0, 0, 0, 0, 0, 0};
  const u64* KR = keys + (size_t)r * 1000;
#pragma unroll
  for (int m = 0; m < 16; ++m) {
    int i = lane + (m << 6);
    if (i < 1000) {
      u64 k = KR[i];
      if (k > t8[7]) {
        t8[7] = k;
#pragma unroll
        for (int e = 7; e > 0; --e) {
          u64 hi = t8[e - 1], lo = t8[e];
          t8[e - 1] = (lo > hi) ? lo : hi;
          t8[e]     = (lo > hi) ? hi : lo;
        }
      }
    }
  }
  const int mycand = lane >> 2;
  u64 myw = 0;
#pragma unroll
  for (int it = 0; it < NCAND; ++it) {
    u64 bmax = t8[0];
#pragma unroll
    for (int o = 32; o; o >>= 1) {
      u64 x = __shfl_xor(bmax, o);
      if (x > bmax) bmax = x;
    }
    if (it == mycand) myw = bmax;
    if (t8[0] == bmax) {
#pragma unroll
      for (int e = 0; e < 7; ++e) t8[e] = t8[e + 1];
      t8[7] = 0;
    }
  }
  const int myvi = (int)(~(u32)(myw & 0xffffffffu));
  float mysum;
  {
    const float4* wrow = (const float4*)(W_out + (size_t)myvi * HD);
    const float4* rf = (const float4*)row_f;
    const int q = lane & 3;
    float s = 0.f;
#pragma unroll
    for (int m2 = 0; m2 < 64; ++m2) {
      float4 a = rf[q + m2 * 4];
      float4 bb = wrow[q + m2 * 4];
      s += a.x * bb.x; s += a.y * bb.y; s += a.z * bb.z; s += a.w * bb.w;
    }
    s += __shfl_xor(s, 1);
    s += __shfl_xor(s, 2);
    mysum = s + b_out[myvi];
  }
  float v[NCAND]; int vi[NCAND];
#pragma unroll
  for (int c = 0; c < NCAND; ++c) {
    v[c] = __shfl(mysum, c * 4);
    vi[c] = __shfl(myvi, c * 4);
  }
  if (lane == 0) {
#pragma unroll
    for (int a = 0; a < 8; ++a)
#pragma unroll
      for (int b2 = a + 1; b2 < NCAND; ++b2) {
        bool sw = (v[b2] > v[a]) || (v[b2] == v[a] && vi[b2] < vi[a]);
        if (sw) {
          float tf = v[a]; v[a] = v[b2]; v[b2] = tf;
          int ti = vi[a]; vi[a] = vi[b2]; vi[b2] = ti;
        }
      }
    const float M = v[0];
    const float TINY = 1.17549435e-38f;
    float best = -3.4e38f; int bi = 0;
#pragma unroll
    for (int k = 0; k < 8; ++k) {
      float lp = v[k] - M;
      u32 bits = jax_random_bits((u32)(r * 8 + k));
      float f = __uint_as_float((bits >> 9) | 0x3f800000u) - 1.0f;
      float u = f * (1.0f - TINY) + TINY;
      u = fmaxf(TINY, u);
      float g = -logf(-logf(u));
      float s = g + lp;
      if (s > best) { best = s; bi = k; }
    }
    int t = r >> 6, b = r & 63;
    out[b * TSTEP + t] = vi[bi];
  }
}

extern "C" void kernel_launch(void* const* d_in, const int* in_sizes, int n_in,
                              void* d_out, int out_size, void* d_ws, size_t ws_size,
                              hipStream_t stream) {
  (void)in_sizes; (void)n_in; (void)out_size; (void)ws_size;
  const float* vectors = (const float*)d_in[0];
  const float* W_fc_in = (const float*)d_in[1];
  const float* b_fc_in = (const float*)d_in[2];
  const float* W_ih    = (const float*)d_in[3];
  const float* W_hh    = (const float*)d_in[4];
  const float* b_ih    = (const float*)d_in[5];
  const float* b_hh    = (const float*)d_in[6];
  const float* W_out   = (const float*)d_in[7];
  const float* b_out   = (const float*)d_in[8];
  int* out = (int*)d_out;

  char* w = (char*)d_ws;
  float* h = (float*)w;          w += (size_t)BBATCH * HD * 4;        // 256 KB
  float* outs = (float*)w;       w += (size_t)NROWS * HD * 4;         // 8 MB
  ushort* outs_bf = (ushort*)w;  w += (size_t)NROWS * HD * 2;         // 4 MB
  ushort* Wbf = (ushort*)w;      w += (size_t)VOCAB * HD * 2;         // 65.5 MB
  // X region: i8 W planes live through the GRU; keys (16 MB) aliases after.
  char* X = w;                   w += (size_t)4 * GATE6 * HD;         // 25.2 MB
  i8* Wq = (i8*)X;
  u64* keys = (u64*)X;                                               // alias
  i8* hQA = (i8*)w;              w += (size_t)4 * BBATCH * HD;        // 256 KB
  i8* hQB = (i8*)w;              w += (size_t)4 * BBATCH * HD;        // 256 KB
  float* part = (float*)w;       // fc_in partials: 4*64*1024 fp32 = 1 MB

  // one-time weight conversions
  tobf16<<<4096, 256, 0, stream>>>(W_out, Wbf, VOCAB * HD / 8);
  quantW_i8<<<GATE6 * (HD / 8) / 256, 256, 0, stream>>>(W_ih, W_hh, Wq);

  // fc_in: h0 = vectors @ W_fc_in^T + b_fc_in  (fp32, split-K=4)
  gemm64_nt<<<dim3(32, 4), 256, 0, stream>>>(vectors, W_fc_in, part);
  combine_fcin<<<256, 256, 0, stream>>>(part, b_fc_in, h, hQA);

  // 32 GRU steps: exact-int8 MFMA, ping-pong h planes, no LDS, no staging
  for (int t = 0; t < TSTEP; ++t) {
    const i8* hin = (t & 1) ? hQB : hQA;
    i8* hout = (t & 1) ? hQA : hQB;
    gru_step<<<256, 128, 0, stream>>>(Wq, b_ih, b_hh, h, outs, outs_bf,
                                      hin, hout, t);
  }

  // bf16 MFMA prefilter over the vocab (cb-per-XCD swizzle)
  gemm_out_mfma<<<dim3(8, 500), 256, 0, stream>>>(outs_bf, Wbf, b_out, keys);

  // per-row top-16 select + exact fp32 rescore + Threefry/Gumbel sampling
  merge_sample2<<<NROWS, 64, 0, stream>>>(keys, outs, W_out, b_out, out);
}